// Round 1
// baseline (233.470 us; speedup 1.0000x reference)
//
#include <hip/hip_runtime.h>

#define B_ 4
#define S_ 2048
#define E_ 512
#define H_ 8
#define HD_ 64

typedef float f32x4 __attribute__((ext_vector_type(4)));
typedef __bf16 bf16x8 __attribute__((ext_vector_type(8)));

#define MFMA16(a, b, c) __builtin_amdgcn_mfma_f32_16x16x32_bf16((a), (b), (c), 0, 0, 0)

__device__ __forceinline__ unsigned f2bfu(float f) {
  union { float f; unsigned u; } x; x.f = f;
  return (x.u + 0x8000u) >> 16;
}
__device__ __forceinline__ unsigned pk2bf(float lo, float hi) {
  union { float f; unsigned u; } a, b; a.f = lo; b.f = hi;
  return ((b.u + 0x8000u) & 0xFFFF0000u) | ((a.u + 0x8000u) >> 16);
}
__device__ __forceinline__ float bf2f(unsigned short s) {
  union { unsigned u; float f; } x; x.u = ((unsigned)s) << 16;
  return x.f;
}
__device__ __forceinline__ float fast_exp2(float x) {
  float r;
  __asm__("v_exp_f32 %0, %1" : "=v"(r) : "v"(x));
  return r;
}
// async global->LDS, 16B per lane. LDS dest = wave-uniform base + lane*16.
__device__ __forceinline__ void gload_lds16(const unsigned short* g, unsigned short* l) {
  __builtin_amdgcn_global_load_lds(
      (const __attribute__((address_space(1))) unsigned int*)g,
      (__attribute__((address_space(3))) unsigned int*)l, 16, 0, 0);
}

// ---------------------------------------------------------------------------
// Fused input conversion. blocks 0..2047: x -> xb (bf16).
// blocks 2048..2431: W (128/matrix); 2432..2495: Er (d-permuted); 2496: zero row.
// ---------------------------------------------------------------------------
__global__ __launch_bounds__(256) void conv_all(
    const float* __restrict__ x, const float* __restrict__ Wq,
    const float* __restrict__ Wk, const float* __restrict__ Wv,
    const float* __restrict__ Er, unsigned short* __restrict__ xb,
    unsigned short* __restrict__ wb, unsigned short* __restrict__ erb)
{
  const int bid = blockIdx.x, tid = threadIdx.x;
  if (bid < 2048) {
    size_t i = ((size_t)bid * 256 + tid) * 8;
    float4 f0 = *(const float4*)&x[i];
    float4 f1 = *(const float4*)&x[i + 4];
    uint4 o;
    o.x = pk2bf(f0.x, f0.y); o.y = pk2bf(f0.z, f0.w);
    o.z = pk2bf(f1.x, f1.y); o.w = pk2bf(f1.z, f1.w);
    *(uint4*)&xb[i] = o;
  } else if (bid < 2432) {
    int wz = bid - 2048;
    int z = wz >> 7, mi = wz & 127;
    const float* src = (z == 0) ? Wq : (z == 1) ? Wk : Wv;
    size_t off = (size_t)mi * 2048 + tid * 8;
    float4 f0 = *(const float4*)&src[off];
    float4 f1 = *(const float4*)&src[off + 4];
    uint4 o;
    o.x = pk2bf(f0.x, f0.y); o.y = pk2bf(f0.z, f0.w);
    o.z = pk2bf(f1.x, f1.y); o.w = pk2bf(f1.z, f1.w);
    *(uint4*)&wb[(size_t)z * 262144 + off] = o;
  } else if (bid < 2496) {
    size_t off = (size_t)(bid - 2432) * 2048 + tid * 8;
    int row = (int)(off >> 6), d0 = (int)(off & 63);
    float4 f0 = *(const float4*)&Er[off];
    float4 f1 = *(const float4*)&Er[off + 4];
    float vals[8] = {f0.x, f0.y, f0.z, f0.w, f1.x, f1.y, f1.z, f1.w};
#pragma unroll
    for (int j = 0; j < 8; ++j) {
      int d = d0 + j;
      int dp = (d & 15) * 4 + (d >> 4);
      erb[(size_t)row * 64 + dp] = (unsigned short)f2bfu(vals[j]);
    }
  } else {
    if (tid < 8) *(uint4*)&erb[2048 * 64 + tid * 8] = make_uint4(0, 0, 0, 0);
  }
}

// ---------------------------------------------------------------------------
// QKV projection, pure-bf16 MFMA with global_load_lds staging.
// out[z] = bf16(xb @ wb[z]^T). M=8192,N=512,K=512. grid (64,4,3), 256 thr.
// ALL z: output d-axis permuted within 64-blocks (d' = (d&15)*4 + d>>4)
// -> packed b64 stores. Q pre-scaled by 512^-0.5 * log2(e).
// V's permutation is undone (free) inside v_transpose's row relabel.
// ---------------------------------------------------------------------------
__global__ __launch_bounds__(256) void qkv_gemm_mfma(
    const unsigned short* __restrict__ xb, const unsigned short* __restrict__ wb,
    unsigned short* __restrict__ qkvb)
{
  const int z = blockIdx.z;
  const unsigned short* W = wb + (size_t)z * 262144;
  unsigned short* out = qkvb + (size_t)z * (8192u * 512u);
  const int m0 = blockIdx.x * 128, n0 = blockIdx.y * 128;

  __shared__ __align__(16) unsigned short As[128 * 64];
  __shared__ __align__(16) unsigned short Bs[128 * 64];

  const int tid = threadIdx.x;
  const int w = tid >> 6, l = tid & 63, lm = l & 15, lq = l >> 4;
  const int wm = w & 1, wn = w >> 1;

  union u4bf { uint4 u; bf16x8 v; };
  f32x4 acc[4][4];
#pragma unroll
  for (int a = 0; a < 4; ++a)
#pragma unroll
    for (int b = 0; b < 4; ++b) acc[a][b] = (f32x4){0.f, 0.f, 0.f, 0.f};

  for (int k0 = 0; k0 < 512; k0 += 64) {
    const unsigned short* xa = xb + (size_t)m0 * 512 + k0;
    const unsigned short* wz = W + (size_t)n0 * 512 + k0;
    __syncthreads();
#pragma unroll
    for (int rr = 0; rr < 4; ++rr) {
      int cb = rr * 256 + w * 64;
      int s = cb + l;
      int row = s >> 3, c = (s & 7) ^ (row & 7);
      gload_lds16(&xa[(size_t)row * 512 + c * 8], &As[cb * 8]);
      gload_lds16(&wz[(size_t)row * 512 + c * 8], &Bs[cb * 8]);
    }
    __syncthreads();
#pragma unroll
    for (int ka = 0; ka < 2; ++ka) {
      u4bf af[4];
#pragma unroll
      for (int mt = 0; mt < 4; ++mt) {
        int row = wm * 64 + mt * 16 + lm;
        af[mt].u = *(const uint4*)&As[row * 64 + (((ka * 4 + lq) ^ (row & 7)) * 8)];
      }
#pragma unroll
      for (int nt = 0; nt < 4; ++nt) {
        int row = wn * 64 + nt * 16 + lm;
        u4bf bfv;
        bfv.u = *(const uint4*)&Bs[row * 64 + (((ka * 4 + lq) ^ (row & 7)) * 8)];
#pragma unroll
        for (int mt = 0; mt < 4; ++mt) acc[mt][nt] = MFMA16(af[mt].v, bfv.v, acc[mt][nt]);
      }
    }
  }
  const float m = (z == 0) ? 0.06376695f : 1.0f;  // 512^-0.5 * log2(e) for Q
#pragma unroll
  for (int mt = 0; mt < 4; ++mt)
#pragma unroll
    for (int reg = 0; reg < 4; ++reg) {
      int row = m0 + wm * 64 + mt * 16 + lq * 4 + reg;
      uint2 v = make_uint2(
          pk2bf(acc[mt][0][reg] * m, acc[mt][1][reg] * m),
          pk2bf(acc[mt][2][reg] * m, acc[mt][3][reg] * m));
      *(uint2*)&out[(size_t)row * 512 + n0 + wn * 64 + lm * 4] = v;
    }
}

// ---------------------------------------------------------------------------
// V transpose with t-permutation baked in; input V arrives d-permuted
// (d' = (d&15)*4 + d>>4) so the output row is relabeled d = (d'&3)*16+(d'>>2)
// (free). grid (32, 8, 4), 256 thr.
// ---------------------------------------------------------------------------
__global__ __launch_bounds__(256) void v_transpose(
    const unsigned short* __restrict__ v, unsigned short* __restrict__ vt)
{
  const int s0 = blockIdx.x * 64, c0 = blockIdx.y * 64, b = blockIdx.z;
  __shared__ __align__(16) unsigned short T[64 * 72];
  const int tid = threadIdx.x;
  for (int idx = tid; idx < 512; idx += 256) {
    int r = idx >> 3, c8 = (idx & 7) * 8;
    *(uint4*)&T[r * 72 + c8] =
        *(const uint4*)&v[(size_t)(b * 2048 + s0 + r) * 512 + c0 + c8];
  }
  __syncthreads();
  for (int idx = tid; idx < 512; idx += 256) {
    int dp = idx >> 3, s8 = (idx & 7) * 8;
    int d = (dp & 3) * 16 + (dp >> 2);  // un-permute
    union { unsigned short u[8]; uint4 q; } tmp;
#pragma unroll
    for (int j = 0; j < 8; ++j) {
      int p = s8 + j;
      int tsrc = (p & 3) * 16 + (p >> 2);
      tmp.u[j] = T[tsrc * 72 + dp];
    }
    *(uint4*)&vt[((size_t)(b * 512) + c0 + d) * 2048 + s0 + s8] = tmp.q;
  }
}

// ---------------------------------------------------------------------------
// Fused attention — R7: software-pipelined staging.
//   - Ks double-buffered; K(tb+1) + V(tb) staging issued at TOP of iter tb,
//     before QK. The vmcnt(0) drain moves to B1.5 (pre-PV), covered by
//     QK (8 MFMA) + rslab (10 MFMA) + gather/exp (~600+ cy of work).
//   - B1 (pre-gather) is lgkmcnt-only: Rx ds_writes visible; staging
//     (vmcnt-counted) stays in flight across it.
//   - B2 (end) is a plain s_barrier: protects VTs/Rx against next-iter
//     overwrites; all DS reads are consumed (compiler lgkm waits) before
//     any wave reaches it.
//   - setprio(1) around QK/PV MFMA clusters (T5; role-diverse waves now).
//   - Rx stride 68 -> 66 shorts (132 B = 33 banks, odd): gather reads and
//     rslab writes spread over all 32 banks instead of even banks only.
// Circular Rx[slot=ai&127][isel], stride 66:
//   ai<64: Er[1984+ai]; ai==64: zero row erb[2048]; ai>64: Er[ai-65], isel=il+1.
// LDS: 16K (Ks x2) + 8K (VTs) + 9.2K (Ps) + 16.9K (Rx) = 50.7K -> 3 blocks/CU.
// ---------------------------------------------------------------------------
__global__ __launch_bounds__(256, 3) void attn_mfma(
    const unsigned short* __restrict__ qw, const unsigned short* __restrict__ kw,
    const unsigned short* __restrict__ vt, const unsigned short* __restrict__ erb,
    float* __restrict__ out)
{
  const int qb = blockIdx.x, bh = blockIdx.y;
  const int b = bh >> 3, h = bh & 7;
  const int i0 = qb * 64;

  __shared__ __align__(16) unsigned short Ks[2][64 * 64];  // [t][d'] swizzled, dbuf
  __shared__ __align__(16) unsigned short VTs[64 * 64];    // [d][t'] swizzled
  __shared__ __align__(16) unsigned short Ps[64 * 72];     // P [i][t'] wave-private rows
  __shared__ __align__(16) unsigned short Rx[128 * 66];    // [slot][isel]

  const int tid = threadIdx.x;
  const int w = tid >> 6, l = tid & 63, lm = l & 15, lq = l >> 4;

  const unsigned short* qbase = qw + ((size_t)(b * 2048)) * 512 + h * 64;
  const unsigned short* kbase = kw + ((size_t)(b * 2048)) * 512 + h * 64;
  const unsigned short* vtb = vt + ((size_t)(b * 512 + h * 64)) * 2048;

  union u4bf { uint4 u; bf16x8 v; };

  u4bf ones;
  ones.u = make_uint4(0x3F803F80u, 0x3F803F80u, 0x3F803F80u, 0x3F803F80u);

  // ---- loop-invariant address constants ----
  const int ko0 = (lq ^ (lm & 7)) * 8;        // swizzled frag offset, ka=0
  const int ko1 = ((4 + lq) ^ (lm & 7)) * 8;  // ka=1
  const int apa = (w * 16 + lm) * 72 + lq * 8;  // ap read base (ka*32 added)
  // gather constants: cn[reg][nt] = 63 + lm - il + 16*nt, il = w*16+lq*4+reg
  int cn0[4], il_[4], psa[4];
#pragma unroll
  for (int reg = 0; reg < 4; ++reg) {
    il_[reg] = w * 16 + lq * 4 + reg;
    cn0[reg] = 63 + lm - il_[reg];
    psa[reg] = il_[reg] * 72 + lm * 4;
  }

  // ---- wave's own QK A-fragment ----
  u4bf aqw[2];
  {
    int gi = i0 + w * 16 + lm;
    aqw[0].u = *(const uint4*)&qbase[(size_t)gi * 512 + lq * 8];
    aqw[1].u = *(const uint4*)&qbase[(size_t)gi * 512 + 32 + lq * 8];
  }
  // ---- Q-ext fragments for rslab (rows rt*16+lm; >64 or OOB -> 0),
  //      constant-indexed ONLY (R2 lesson) ----
  u4bf aq[5][2];
#pragma unroll
  for (int rt = 0; rt < 5; ++rt) {
    int row = rt * 16 + lm, gi = i0 + row;
#pragma unroll
    for (int ka = 0; ka < 2; ++ka) {
      if (row <= 64 && gi < 2048)
        aq[rt][ka].u = *(const uint4*)&qbase[(size_t)gi * 512 + ka * 32 + lq * 8];
      else
        aq[rt][ka].u = make_uint4(0, 0, 0, 0);
    }
  }

  auto stageTile = [&](const unsigned short* srcBase, size_t srcStride,
                       unsigned short* dst) {
#pragma unroll
    for (int rr = 0; rr < 2; ++rr) {
      int cb = rr * 256 + w * 64;
      int s = cb + l;
      int row = s >> 3, c = (s & 7) ^ (row & 7);
      gload_lds16(&srcBase[(size_t)row * srcStride + c * 8], &dst[cb * 8]);
    }
  };
  auto loadBe = [&](int A0, u4bf& be0, u4bf& be1) {
    int ai = A0 + w * 16 + lm;
    int g = (ai < 64) ? (1984 + ai) : (ai == 64 ? 2048 : ai - 65);
    const unsigned short* ep = &erb[(size_t)g * 64];
    be0.u = *(const uint4*)&ep[lq * 8];
    be1.u = *(const uint4*)&ep[32 + lq * 8];
  };
  auto rslabCompute = [&](int A0, u4bf be0, u4bf be1) {
    f32x4 rc[5];
#pragma unroll
    for (int rt = 0; rt < 5; ++rt) rc[rt] = (f32x4){0.f, 0.f, 0.f, 0.f};
    rc[0] = MFMA16(aq[0][0].v, be0.v, rc[0]);
    rc[0] = MFMA16(aq[0][1].v, be1.v, rc[0]);
    rc[1] = MFMA16(aq[1][0].v, be0.v, rc[1]);
    rc[1] = MFMA16(aq[1][1].v, be1.v, rc[1]);
    rc[2] = MFMA16(aq[2][0].v, be0.v, rc[2]);
    rc[2] = MFMA16(aq[2][1].v, be1.v, rc[2]);
    rc[3] = MFMA16(aq[3][0].v, be0.v, rc[3]);
    rc[3] = MFMA16(aq[3][1].v, be1.v, rc[3]);
    rc[4] = MFMA16(aq[4][0].v, be0.v, rc[4]);
    rc[4] = MFMA16(aq[4][1].v, be1.v, rc[4]);
    int slot = (A0 + w * 16 + lm) & 127;
    unsigned short* rp = &Rx[slot * 66 + lq * 4];
    *(unsigned*)&rp[0]  = pk2bf(rc[0][0], rc[0][1]);
    *(unsigned*)&rp[2]  = pk2bf(rc[0][2], rc[0][3]);
    *(unsigned*)&rp[16] = pk2bf(rc[1][0], rc[1][1]);
    *(unsigned*)&rp[18] = pk2bf(rc[1][2], rc[1][3]);
    *(unsigned*)&rp[32] = pk2bf(rc[2][0], rc[2][1]);
    *(unsigned*)&rp[34] = pk2bf(rc[2][2], rc[2][3]);
    *(unsigned*)&rp[48] = pk2bf(rc[3][0], rc[3][1]);
    *(unsigned*)&rp[50] = pk2bf(rc[3][2], rc[3][3]);
    if (lq == 0) Rx[slot * 66 + 64] = (unsigned short)f2bfu(rc[4][0]);
  };

  // ---- prefill Rx with ai in [-i0, -i0+127] (disjoint slots) ----
  {
    u4bf b0, b1;
    loadBe(-i0, b0, b1);
    rslabCompute(-i0, b0, b1);
    loadBe(-i0 + 64, b0, b1);
    rslabCompute(-i0 + 64, b0, b1);
  }
  // prefetch Er B-fragments for tb=1 (A0 = -i0+127)
  u4bf pb0, pb1;
  loadBe(-i0 + 127, pb0, pb1);

  // stage K tile for tb=0 into Ks[0]
  stageTile(kbase, 512, Ks[0]);
  __syncthreads();  // full drain: Rx prefill visible, Ks[0] landed

  f32x4 O[5];  // O[4] = row-sum l accumulator
#pragma unroll
  for (int a = 0; a < 5; ++a) O[a] = (f32x4){0.f, 0.f, 0.f, 0.f};

  int cur = 0;
  for (int tb = 0; tb < 32; ++tb) {
    const int t0 = tb * 64, dbase = t0 - i0;

    // ---- issue ALL VMEM for this iter up front (drain is at B1.5) ----
    if (tb < 31) stageTile(kbase + (size_t)(t0 + 64) * 512, 512, Ks[cur ^ 1]);
    stageTile(vtb + t0, 2048, VTs);

    // ---- QK^T from Ks[cur] (staged last iter, drained at prev B1.5) ----
    f32x4 sc[4];
    __builtin_amdgcn_s_setprio(1);
#pragma unroll
    for (int nt = 0; nt < 4; ++nt) {
      int rb = (nt * 16 + lm) * 64;
      u4bf bk0, bk1;
      bk0.u = *(const uint4*)&Ks[cur][rb + ko0];
      bk1.u = *(const uint4*)&Ks[cur][rb + ko1];
      sc[nt] = (f32x4){0.f, 0.f, 0.f, 0.f};
      sc[nt] = MFMA16(aqw[0].v, bk0.v, sc[nt]);
      sc[nt] = MFMA16(aqw[1].v, bk1.v, sc[nt]);
    }
    __builtin_amdgcn_s_setprio(0);

    // ---- rslab writes Rx rows [dbase+63, dbase+126] for THIS iter's gather;
    //      then prefetch Er fragments for next iter ----
    if (tb > 0) {
      rslabCompute(dbase + 63, pb0, pb1);
      if (tb < 31) loadBe(dbase + 127, pb0, pb1);
    }

    // ---- B1: Rx ds_writes visible; staging stays in flight (vmcnt) ----
    __asm__ __volatile__("s_waitcnt lgkmcnt(0)" ::: "memory");
    __builtin_amdgcn_s_barrier();
    __builtin_amdgcn_sched_barrier(0);

    // ---- skew gather + exp2, packed b64 P-write (wave-private rows) ----
#pragma unroll
    for (int reg = 0; reg < 4; ++reg) {
      const int aib = dbase + cn0[reg];
      const int il = il_[reg];
      float pv[4];
#pragma unroll
      for (int nt = 0; nt < 4; ++nt) {
        int ai = aib + nt * 16;
        int isel = il + (ai >= 65 ? 1 : 0);
        float rel = bf2f(Rx[(ai & 127) * 66 + isel]);
        pv[nt] = fast_exp2(sc[nt][reg] + rel);
      }
      *(uint2*)&Ps[psa[reg]] =
          make_uint2(pk2bf(pv[0], pv[1]), pk2bf(pv[2], pv[3]));
    }
    __asm__ __volatile__("" ::: "memory");  // same-wave DS RAW: in-order DS pipe

    // ---- B1.5: drain staging (covered by QK+rslab+gather), then PV ----
    __asm__ __volatile__("s_waitcnt vmcnt(0)" ::: "memory");
    __builtin_amdgcn_s_barrier();
    __builtin_amdgcn_sched_barrier(0);

    // ---- PV + l (ones from registers) ----
    __builtin_amdgcn_s_setprio(1);
#pragma unroll
    for (int ka = 0; ka < 2; ++ka) {
      u4bf ap;
      ap.u = *(const uint4*)&Ps[apa + ka * 32];
#pragma unroll
      for (int nt = 0; nt < 4; ++nt) {
        int rb = (nt * 16 + lm) * 64;
        u4bf bv;
        bv.u = *(const uint4*)&VTs[rb + (ka == 0 ? ko0 : ko1)];
        O[nt] = MFMA16(ap.v, bv.v, O[nt]);
      }
      O[4] = MFMA16(ap.v, ones.v, O[4]);
    }
    __builtin_amdgcn_s_setprio(0);

    // ---- B2: protect VTs/Rx against next-iter overwrites (plain barrier;
    //      all DS reads already consumed via compiler lgkm waits) ----
    __builtin_amdgcn_s_barrier();
    cur ^= 1;
  }

  // epilogue: every lane holds l in O[4][reg]
  float* ob = out + ((size_t)(b * 2048) + i0) * 512 + h * 64;
#pragma unroll
  for (int reg = 0; reg < 4; ++reg) {
    float inv = 1.f / O[4][reg];
#pragma unroll
    for (int nt = 0; nt < 4; ++nt)
      ob[(size_t)il_[reg] * 512 + nt * 16 + lm] = O[nt][reg] * inv;
  }
}

// ---------------------------------------------------------------------------
// In-place LayerNorm over E=512 per (b,s) row. grid 8192, block 256.
// ---------------------------------------------------------------------------
__global__ __launch_bounds__(256) void ln_kernel(
    float* __restrict__ io, const float* __restrict__ gamma,
    const float* __restrict__ beta)
{
  const int row = blockIdx.x;
  float* xr = io + (size_t)row * 512;
  const int tid = threadIdx.x;
  float2 v = *(const float2*)&xr[tid * 2];
  float s = v.x + v.y;
  float sq = v.x * v.x + v.y * v.y;
#pragma unroll
  for (int off = 1; off < 64; off <<= 1) {
    s += __shfl_xor(s, off, 64);
    sq += __shfl_xor(sq, off, 64);
  }
  __shared__ float red[8];
  const int wid = tid >> 6, lane = tid & 63;
  if (lane == 0) { red[wid] = s; red[wid + 4] = sq; }
  __syncthreads();
  s = red[0] + red[1] + red[2] + red[3];
  sq = red[4] + red[5] + red[6] + red[7];
  const float mean = s * (1.f / 512.f);
  float var = sq * (1.f / 512.f) - mean * mean;
  var = fmaxf(var, 0.f);
  const float rstd = rsqrtf(var + 1e-5f);
  float2 g = *(const float2*)&gamma[tid * 2];
  float2 be = *(const float2*)&beta[tid * 2];
  float2 o;
  o.x = (v.x - mean) * rstd * g.x + be.x;
  o.y = (v.y - mean) * rstd * g.y + be.y;
  *(float2*)&xr[tid * 2] = o;
}

extern "C" void kernel_launch(void* const* d_in, const int* in_sizes, int n_in,
                              void* d_out, int out_size, void* d_ws, size_t ws_size,
                              hipStream_t stream) {
  const float* x     = (const float*)d_in[0];
  const float* Wq    = (const float*)d_in[1];
  const float* Wk    = (const float*)d_in[2];
  const float* Wv    = (const float*)d_in[3];
  const float* Er    = (const float*)d_in[4];
  const float* gamma = (const float*)d_in[5];
  const float* beta  = (const float*)d_in[6];
  float* out = (float*)d_out;

  // ws layout (bf16 shorts): qkv 3*8192*512 | vT 4*512*2048 | erb 2049*64 |
  //                          xb 8192*512 | wb 3*512*512      (~41.8 MB)
  unsigned short* qkvb = (unsigned short*)d_ws;
  unsigned short* vtb  = qkvb + (size_t)3 * 8192 * 512;
  unsigned short* erb  = vtb + (size_t)4 * 512 * 2048;
  unsigned short* xb   = erb + (size_t)2049 * 64;
  unsigned short* wb   = xb + (size_t)8192 * 512;
  unsigned short* vb   = qkvb + (size_t)2 * 8192 * 512;

  conv_all<<<dim3(2497), 256, 0, stream>>>(x, Wq, Wk, Wv, Er, xb, wb, erb);
  qkv_gemm_mfma<<<dim3(64, 4, 3), 256, 0, stream>>>(xb, wb, qkvb);
  v_transpose<<<dim3(32, 8, 4), 256, 0, stream>>>(vb, vtb);
  attn_mfma<<<dim3(32, 32), 256, 0, stream>>>(qkvb, qkvb + (size_t)8192 * 512, vtb, erb, out);
  ln_kernel<<<dim3(8192), 256, 0, stream>>>(out, gamma, beta);
}

// Round 2
// 222.175 us; speedup vs baseline: 1.0508x; 1.0508x over previous
//
#include <hip/hip_runtime.h>

#define B_ 4
#define S_ 2048
#define E_ 512
#define H_ 8
#define HD_ 64

typedef float f32x4 __attribute__((ext_vector_type(4)));
typedef __bf16 bf16x8 __attribute__((ext_vector_type(8)));

#define MFMA16(a, b, c) __builtin_amdgcn_mfma_f32_16x16x32_bf16((a), (b), (c), 0, 0, 0)

__device__ __forceinline__ unsigned f2bfu(float f) {
  union { float f; unsigned u; } x; x.f = f;
  return (x.u + 0x8000u) >> 16;
}
__device__ __forceinline__ unsigned pk2bf(float lo, float hi) {
  union { float f; unsigned u; } a, b; a.f = lo; b.f = hi;
  return ((b.u + 0x8000u) & 0xFFFF0000u) | ((a.u + 0x8000u) >> 16);
}
__device__ __forceinline__ float bf2f(unsigned short s) {
  union { unsigned u; float f; } x; x.u = ((unsigned)s) << 16;
  return x.f;
}
__device__ __forceinline__ float fast_exp2(float x) {
  float r;
  __asm__("v_exp_f32 %0, %1" : "=v"(r) : "v"(x));
  return r;
}
// async global->LDS, 16B per lane. LDS dest = wave-uniform base + lane*16.
__device__ __forceinline__ void gload_lds16(const unsigned short* g, unsigned short* l) {
  __builtin_amdgcn_global_load_lds(
      (const __attribute__((address_space(1))) unsigned int*)g,
      (__attribute__((address_space(3))) unsigned int*)l, 16, 0, 0);
}

// ---------------------------------------------------------------------------
// Fused input conversion. blocks 0..2047: x -> xb (bf16).
// blocks 2048..2431: W (128/matrix); 2432..2495: Er (d-permuted); 2496: zero row.
// ---------------------------------------------------------------------------
__global__ __launch_bounds__(256) void conv_all(
    const float* __restrict__ x, const float* __restrict__ Wq,
    const float* __restrict__ Wk, const float* __restrict__ Wv,
    const float* __restrict__ Er, unsigned short* __restrict__ xb,
    unsigned short* __restrict__ wb, unsigned short* __restrict__ erb)
{
  const int bid = blockIdx.x, tid = threadIdx.x;
  if (bid < 2048) {
    size_t i = ((size_t)bid * 256 + tid) * 8;
    float4 f0 = *(const float4*)&x[i];
    float4 f1 = *(const float4*)&x[i + 4];
    uint4 o;
    o.x = pk2bf(f0.x, f0.y); o.y = pk2bf(f0.z, f0.w);
    o.z = pk2bf(f1.x, f1.y); o.w = pk2bf(f1.z, f1.w);
    *(uint4*)&xb[i] = o;
  } else if (bid < 2432) {
    int wz = bid - 2048;
    int z = wz >> 7, mi = wz & 127;
    const float* src = (z == 0) ? Wq : (z == 1) ? Wk : Wv;
    size_t off = (size_t)mi * 2048 + tid * 8;
    float4 f0 = *(const float4*)&src[off];
    float4 f1 = *(const float4*)&src[off + 4];
    uint4 o;
    o.x = pk2bf(f0.x, f0.y); o.y = pk2bf(f0.z, f0.w);
    o.z = pk2bf(f1.x, f1.y); o.w = pk2bf(f1.z, f1.w);
    *(uint4*)&wb[(size_t)z * 262144 + off] = o;
  } else if (bid < 2496) {
    size_t off = (size_t)(bid - 2432) * 2048 + tid * 8;
    int row = (int)(off >> 6), d0 = (int)(off & 63);
    float4 f0 = *(const float4*)&Er[off];
    float4 f1 = *(const float4*)&Er[off + 4];
    float vals[8] = {f0.x, f0.y, f0.z, f0.w, f1.x, f1.y, f1.z, f1.w};
#pragma unroll
    for (int j = 0; j < 8; ++j) {
      int d = d0 + j;
      int dp = (d & 15) * 4 + (d >> 4);
      erb[(size_t)row * 64 + dp] = (unsigned short)f2bfu(vals[j]);
    }
  } else {
    if (tid < 8) *(uint4*)&erb[2048 * 64 + tid * 8] = make_uint4(0, 0, 0, 0);
  }
}

// ---------------------------------------------------------------------------
// QKV projection, pure-bf16 MFMA with global_load_lds staging.
// out[z] = bf16(xb @ wb[z]^T). M=8192,N=512,K=512. grid (64,4,3), 256 thr.
// ALL z: output d-axis permuted within 64-blocks (d' = (d&15)*4 + d>>4)
// -> packed b64 stores. Q pre-scaled by 512^-0.5 * log2(e).
// V's permutation is undone (free) inside v_transpose's row relabel.
// ---------------------------------------------------------------------------
__global__ __launch_bounds__(256) void qkv_gemm_mfma(
    const unsigned short* __restrict__ xb, const unsigned short* __restrict__ wb,
    unsigned short* __restrict__ qkvb)
{
  const int z = blockIdx.z;
  const unsigned short* W = wb + (size_t)z * 262144;
  unsigned short* out = qkvb + (size_t)z * (8192u * 512u);
  const int m0 = blockIdx.x * 128, n0 = blockIdx.y * 128;

  __shared__ __align__(16) unsigned short As[128 * 64];
  __shared__ __align__(16) unsigned short Bs[128 * 64];

  const int tid = threadIdx.x;
  const int w = tid >> 6, l = tid & 63, lm = l & 15, lq = l >> 4;
  const int wm = w & 1, wn = w >> 1;

  union u4bf { uint4 u; bf16x8 v; };
  f32x4 acc[4][4];
#pragma unroll
  for (int a = 0; a < 4; ++a)
#pragma unroll
    for (int b = 0; b < 4; ++b) acc[a][b] = (f32x4){0.f, 0.f, 0.f, 0.f};

  for (int k0 = 0; k0 < 512; k0 += 64) {
    const unsigned short* xa = xb + (size_t)m0 * 512 + k0;
    const unsigned short* wz = W + (size_t)n0 * 512 + k0;
    __syncthreads();
#pragma unroll
    for (int rr = 0; rr < 4; ++rr) {
      int cb = rr * 256 + w * 64;
      int s = cb + l;
      int row = s >> 3, c = (s & 7) ^ (row & 7);
      gload_lds16(&xa[(size_t)row * 512 + c * 8], &As[cb * 8]);
      gload_lds16(&wz[(size_t)row * 512 + c * 8], &Bs[cb * 8]);
    }
    __syncthreads();
#pragma unroll
    for (int ka = 0; ka < 2; ++ka) {
      u4bf af[4];
#pragma unroll
      for (int mt = 0; mt < 4; ++mt) {
        int row = wm * 64 + mt * 16 + lm;
        af[mt].u = *(const uint4*)&As[row * 64 + (((ka * 4 + lq) ^ (row & 7)) * 8)];
      }
#pragma unroll
      for (int nt = 0; nt < 4; ++nt) {
        int row = wn * 64 + nt * 16 + lm;
        u4bf bfv;
        bfv.u = *(const uint4*)&Bs[row * 64 + (((ka * 4 + lq) ^ (row & 7)) * 8)];
#pragma unroll
        for (int mt = 0; mt < 4; ++mt) acc[mt][nt] = MFMA16(af[mt].v, bfv.v, acc[mt][nt]);
      }
    }
  }
  const float m = (z == 0) ? 0.06376695f : 1.0f;  // 512^-0.5 * log2(e) for Q
#pragma unroll
  for (int mt = 0; mt < 4; ++mt)
#pragma unroll
    for (int reg = 0; reg < 4; ++reg) {
      int row = m0 + wm * 64 + mt * 16 + lq * 4 + reg;
      uint2 v = make_uint2(
          pk2bf(acc[mt][0][reg] * m, acc[mt][1][reg] * m),
          pk2bf(acc[mt][2][reg] * m, acc[mt][3][reg] * m));
      *(uint2*)&out[(size_t)row * 512 + n0 + wn * 64 + lm * 4] = v;
    }
}

// ---------------------------------------------------------------------------
// V transpose with t-permutation baked in; input V arrives d-permuted
// (d' = (d&15)*4 + d>>4) so the output row is relabeled d = (d'&3)*16+(d'>>2)
// (free). grid (32, 8, 4), 256 thr.
// ---------------------------------------------------------------------------
__global__ __launch_bounds__(256) void v_transpose(
    const unsigned short* __restrict__ v, unsigned short* __restrict__ vt)
{
  const int s0 = blockIdx.x * 64, c0 = blockIdx.y * 64, b = blockIdx.z;
  __shared__ __align__(16) unsigned short T[64 * 72];
  const int tid = threadIdx.x;
  for (int idx = tid; idx < 512; idx += 256) {
    int r = idx >> 3, c8 = (idx & 7) * 8;
    *(uint4*)&T[r * 72 + c8] =
        *(const uint4*)&v[(size_t)(b * 2048 + s0 + r) * 512 + c0 + c8];
  }
  __syncthreads();
  for (int idx = tid; idx < 512; idx += 256) {
    int dp = idx >> 3, s8 = (idx & 7) * 8;
    int d = (dp & 3) * 16 + (dp >> 2);  // un-permute
    union { unsigned short u[8]; uint4 q; } tmp;
#pragma unroll
    for (int j = 0; j < 8; ++j) {
      int p = s8 + j;
      int tsrc = (p & 3) * 16 + (p >> 2);
      tmp.u[j] = T[tsrc * 72 + dp];
    }
    *(uint4*)&vt[((size_t)(b * 512) + c0 + d) * 2048 + s0 + s8] = tmp.q;
  }
}

// ---------------------------------------------------------------------------
// Fused attention — R8: paired Q-tiles, residency-exact grid.
// R7 post-mortem: pipeline restructure neutral (staging drain was already
// hidden by TLP); Rx stride 66 regressed banks -> both reverted. Structure
// below is the proven R5/R6 one (2 full barriers/iter, stride 68).
// NEW: one block = 8 waves = TWO wave-groups of 4; group g owns Q-tile
// qp*2+g. Both groups share the same staged K/V tile in the same tb loop:
//   - grid 512 = EXACTLY 2 blocks/CU of work; LDS 68K -> exactly 2 resident
//     => no 1-block/CU tail phase (old: 4/CU work, 3 resident => 25% of
//     work ran solo at ~1/3 speed).
//   - 4 waves/SIMD steady-state (was 3) => more latency hiding.
//   - K/V L2 traffic and staging issue cost per Q-tile halved.
// LDS: Ks 8K + VTs 8K + Ps[2] 18K + Rx[2] 34K = 68K; VGPR/wave unchanged.
// Circular Rx[g][slot=ai&127][isel], stride 68:
//   ai<64: Er[1984+ai]; ai==64: zero row erb[2048]; ai>64: Er[ai-65], isel=il+1.
// ---------------------------------------------------------------------------
__global__ __launch_bounds__(512, 4) void attn_mfma(
    const unsigned short* __restrict__ qw, const unsigned short* __restrict__ kw,
    const unsigned short* __restrict__ vt, const unsigned short* __restrict__ erb,
    float* __restrict__ out)
{
  const int qp = blockIdx.x, bh = blockIdx.y;
  const int b = bh >> 3, h = bh & 7;

  __shared__ __align__(16) unsigned short Ks[64 * 64];        // [t][d'] swizzled
  __shared__ __align__(16) unsigned short VTs[64 * 64];       // [d][t'] swizzled
  __shared__ __align__(16) unsigned short Ps[2][64 * 72];     // per-group P rows
  __shared__ __align__(16) unsigned short Rx[2][128 * 68];    // per-group [slot][isel]

  const int tid = threadIdx.x;
  const int w = tid >> 6, l = tid & 63, lm = l & 15, lq = l >> 4;
  const int wg = w >> 2, wl = w & 3;   // wave-group (Q-tile), wave-in-group
  const int i0 = (qp * 2 + wg) * 64;

  const unsigned short* qbase = qw + ((size_t)(b * 2048)) * 512 + h * 64;
  const unsigned short* kbase = kw + ((size_t)(b * 2048)) * 512 + h * 64;
  const unsigned short* vtb = vt + ((size_t)(b * 512 + h * 64)) * 2048;

  union u4bf { uint4 u; bf16x8 v; };

  u4bf ones;
  ones.u = make_uint4(0x3F803F80u, 0x3F803F80u, 0x3F803F80u, 0x3F803F80u);

  // ---- loop-invariant address constants ----
  const int ko0 = (lq ^ (lm & 7)) * 8;          // swizzled frag offset, ka=0
  const int ko1 = ((4 + lq) ^ (lm & 7)) * 8;    // ka=1
  const int apa = (wl * 16 + lm) * 72 + lq * 8; // ap read base (ka*32 added)
  unsigned short* PsG = Ps[wg];
  unsigned short* RxG = Rx[wg];
  // gather constants: cn[reg][nt] = 63 + lm - il + 16*nt, il = wl*16+lq*4+reg
  int cn0[4], il_[4], psa[4];
#pragma unroll
  for (int reg = 0; reg < 4; ++reg) {
    il_[reg] = wl * 16 + lq * 4 + reg;
    cn0[reg] = 63 + lm - il_[reg];
    psa[reg] = il_[reg] * 72 + lm * 4;
  }

  // ---- wave's own QK A-fragment ----
  u4bf aqw[2];
  {
    int gi = i0 + wl * 16 + lm;
    aqw[0].u = *(const uint4*)&qbase[(size_t)gi * 512 + lq * 8];
    aqw[1].u = *(const uint4*)&qbase[(size_t)gi * 512 + 32 + lq * 8];
  }
  // ---- Q-ext fragments for rslab (rows rt*16+lm; >64 or OOB -> 0),
  //      constant-indexed ONLY (R2 lesson) ----
  u4bf aq[5][2];
#pragma unroll
  for (int rt = 0; rt < 5; ++rt) {
    int row = rt * 16 + lm, gi = i0 + row;
#pragma unroll
    for (int ka = 0; ka < 2; ++ka) {
      if (row <= 64 && gi < 2048)
        aq[rt][ka].u = *(const uint4*)&qbase[(size_t)gi * 512 + ka * 32 + lq * 8];
      else
        aq[rt][ka].u = make_uint4(0, 0, 0, 0);
    }
  }

  // 8 waves stage a 64x64 tile: one gload_lds16 per wave.
  auto stageTile = [&](const unsigned short* srcBase, size_t srcStride,
                       unsigned short* dst) {
    int cb = w * 64;
    int s = cb + l;
    int row = s >> 3, c = (s & 7) ^ (row & 7);
    gload_lds16(&srcBase[(size_t)row * srcStride + c * 8], &dst[cb * 8]);
  };
  auto loadBe = [&](int A0, u4bf& be0, u4bf& be1) {
    int ai = A0 + wl * 16 + lm;
    int g = (ai < 64) ? (1984 + ai) : (ai == 64 ? 2048 : ai - 65);
    const unsigned short* ep = &erb[(size_t)g * 64];
    be0.u = *(const uint4*)&ep[lq * 8];
    be1.u = *(const uint4*)&ep[32 + lq * 8];
  };
  auto rslabCompute = [&](int A0, u4bf be0, u4bf be1) {
    f32x4 rc[5];
#pragma unroll
    for (int rt = 0; rt < 5; ++rt) rc[rt] = (f32x4){0.f, 0.f, 0.f, 0.f};
    rc[0] = MFMA16(aq[0][0].v, be0.v, rc[0]);
    rc[0] = MFMA16(aq[0][1].v, be1.v, rc[0]);
    rc[1] = MFMA16(aq[1][0].v, be0.v, rc[1]);
    rc[1] = MFMA16(aq[1][1].v, be1.v, rc[1]);
    rc[2] = MFMA16(aq[2][0].v, be0.v, rc[2]);
    rc[2] = MFMA16(aq[2][1].v, be1.v, rc[2]);
    rc[3] = MFMA16(aq[3][0].v, be0.v, rc[3]);
    rc[3] = MFMA16(aq[3][1].v, be1.v, rc[3]);
    rc[4] = MFMA16(aq[4][0].v, be0.v, rc[4]);
    rc[4] = MFMA16(aq[4][1].v, be1.v, rc[4]);
    int slot = (A0 + wl * 16 + lm) & 127;
    unsigned short* rp = &RxG[slot * 68 + lq * 4];
    *(unsigned*)&rp[0]  = pk2bf(rc[0][0], rc[0][1]);
    *(unsigned*)&rp[2]  = pk2bf(rc[0][2], rc[0][3]);
    *(unsigned*)&rp[16] = pk2bf(rc[1][0], rc[1][1]);
    *(unsigned*)&rp[18] = pk2bf(rc[1][2], rc[1][3]);
    *(unsigned*)&rp[32] = pk2bf(rc[2][0], rc[2][1]);
    *(unsigned*)&rp[34] = pk2bf(rc[2][2], rc[2][3]);
    *(unsigned*)&rp[48] = pk2bf(rc[3][0], rc[3][1]);
    *(unsigned*)&rp[50] = pk2bf(rc[3][2], rc[3][3]);
    if (lq == 0) RxG[slot * 68 + 64] = (unsigned short)f2bfu(rc[4][0]);
  };

  // ---- prefill Rx[wg] with ai in [-i0, -i0+127] (disjoint slots) ----
  {
    u4bf b0, b1;
    loadBe(-i0, b0, b1);
    rslabCompute(-i0, b0, b1);
    loadBe(-i0 + 64, b0, b1);
    rslabCompute(-i0 + 64, b0, b1);
  }
  // prefetch Er B-fragments for tb=1 (A0 = -i0+127)
  u4bf pb0, pb1;
  loadBe(-i0 + 127, pb0, pb1);

  f32x4 O[5];  // O[4] = row-sum l accumulator
#pragma unroll
  for (int a = 0; a < 5; ++a) O[a] = (f32x4){0.f, 0.f, 0.f, 0.f};

  for (int tb = 0; tb < 32; ++tb) {
    const int t0 = tb * 64, dbase = t0 - i0;
    __syncthreads();  // (a) prior-iter consumers (QK/PV/gather) done

    stageTile(kbase + (size_t)t0 * 512, 512, Ks);
    stageTile(vtb + t0, 2048, VTs);
    if (tb > 0) {
      rslabCompute(dbase + 63, pb0, pb1);
      if (tb < 31) loadBe(dbase + 127, pb0, pb1);  // prefetch next iter
    }
    __syncthreads();  // (b) staging DMA drained + Rx visible

    // ---- QK^T (hoisted swizzle offsets) ----
    f32x4 sc[4];
#pragma unroll
    for (int nt = 0; nt < 4; ++nt) {
      int rb = (nt * 16 + lm) * 64;
      u4bf bk0, bk1;
      bk0.u = *(const uint4*)&Ks[rb + ko0];
      bk1.u = *(const uint4*)&Ks[rb + ko1];
      sc[nt] = (f32x4){0.f, 0.f, 0.f, 0.f};
      sc[nt] = MFMA16(aqw[0].v, bk0.v, sc[nt]);
      sc[nt] = MFMA16(aqw[1].v, bk1.v, sc[nt]);
    }

    // ---- skew gather + exp2, packed b64 P-write (wave-private rows) ----
#pragma unroll
    for (int reg = 0; reg < 4; ++reg) {
      const int aib = dbase + cn0[reg];
      const int il = il_[reg];
      float pv[4];
#pragma unroll
      for (int nt = 0; nt < 4; ++nt) {
        int ai = aib + nt * 16;
        int isel = il + (ai >= 65 ? 1 : 0);
        float rel = bf2f(RxG[(ai & 127) * 68 + isel]);
        pv[nt] = fast_exp2(sc[nt][reg] + rel);
      }
      *(uint2*)&PsG[psa[reg]] =
          make_uint2(pk2bf(pv[0], pv[1]), pk2bf(pv[2], pv[3]));
    }
    __asm__ __volatile__("" ::: "memory");  // same-wave DS RAW: in-order DS pipe

    // ---- PV + l (ones from registers) ----
#pragma unroll
    for (int ka = 0; ka < 2; ++ka) {
      u4bf ap;
      ap.u = *(const uint4*)&PsG[apa + ka * 32];
#pragma unroll
      for (int nt = 0; nt < 4; ++nt) {
        int rb = (nt * 16 + lm) * 64;
        u4bf bv;
        bv.u = *(const uint4*)&VTs[rb + (ka == 0 ? ko0 : ko1)];
        O[nt] = MFMA16(ap.v, bv.v, O[nt]);
      }
      O[4] = MFMA16(ap.v, ones.v, O[4]);
    }
  }

  // epilogue: every lane holds l in O[4][reg]
  float* ob = out + ((size_t)(b * 2048) + i0) * 512 + h * 64;
#pragma unroll
  for (int reg = 0; reg < 4; ++reg) {
    float inv = 1.f / O[4][reg];
#pragma unroll
    for (int nt = 0; nt < 4; ++nt)
      ob[(size_t)il_[reg] * 512 + nt * 16 + lm] = O[nt][reg] * inv;
  }
}

// ---------------------------------------------------------------------------
// In-place LayerNorm over E=512 per (b,s) row. grid 8192, block 256.
// ---------------------------------------------------------------------------
__global__ __launch_bounds__(256) void ln_kernel(
    float* __restrict__ io, const float* __restrict__ gamma,
    const float* __restrict__ beta)
{
  const int row = blockIdx.x;
  float* xr = io + (size_t)row * 512;
  const int tid = threadIdx.x;
  float2 v = *(const float2*)&xr[tid * 2];
  float s = v.x + v.y;
  float sq = v.x * v.x + v.y * v.y;
#pragma unroll
  for (int off = 1; off < 64; off <<= 1) {
    s += __shfl_xor(s, off, 64);
    sq += __shfl_xor(sq, off, 64);
  }
  __shared__ float red[8];
  const int wid = tid >> 6, lane = tid & 63;
  if (lane == 0) { red[wid] = s; red[wid + 4] = sq; }
  __syncthreads();
  s = red[0] + red[1] + red[2] + red[3];
  sq = red[4] + red[5] + red[6] + red[7];
  const float mean = s * (1.f / 512.f);
  float var = sq * (1.f / 512.f) - mean * mean;
  var = fmaxf(var, 0.f);
  const float rstd = rsqrtf(var + 1e-5f);
  float2 g = *(const float2*)&gamma[tid * 2];
  float2 be = *(const float2*)&beta[tid * 2];
  float2 o;
  o.x = (v.x - mean) * rstd * g.x + be.x;
  o.y = (v.y - mean) * rstd * g.y + be.y;
  *(float2*)&xr[tid * 2] = o;
}

extern "C" void kernel_launch(void* const* d_in, const int* in_sizes, int n_in,
                              void* d_out, int out_size, void* d_ws, size_t ws_size,
                              hipStream_t stream) {
  const float* x     = (const float*)d_in[0];
  const float* Wq    = (const float*)d_in[1];
  const float* Wk    = (const float*)d_in[2];
  const float* Wv    = (const float*)d_in[3];
  const float* Er    = (const float*)d_in[4];
  const float* gamma = (const float*)d_in[5];
  const float* beta  = (const float*)d_in[6];
  float* out = (float*)d_out;

  // ws layout (bf16 shorts): qkv 3*8192*512 | vT 4*512*2048 | erb 2049*64 |
  //                          xb 8192*512 | wb 3*512*512      (~41.8 MB)
  unsigned short* qkvb = (unsigned short*)d_ws;
  unsigned short* vtb  = qkvb + (size_t)3 * 8192 * 512;
  unsigned short* erb  = vtb + (size_t)4 * 512 * 2048;
  unsigned short* xb   = erb + (size_t)2049 * 64;
  unsigned short* wb   = xb + (size_t)8192 * 512;
  unsigned short* vb   = qkvb + (size_t)2 * 8192 * 512;

  conv_all<<<dim3(2497), 256, 0, stream>>>(x, Wq, Wk, Wv, Er, xb, wb, erb);
  qkv_gemm_mfma<<<dim3(64, 4, 3), 256, 0, stream>>>(xb, wb, qkvb);
  v_transpose<<<dim3(32, 8, 4), 256, 0, stream>>>(vb, vtb);
  attn_mfma<<<dim3(16, 32), 512, 0, stream>>>(qkvb, qkvb + (size_t)8192 * 512, vtb, erb, out);
  ln_kernel<<<dim3(8192), 256, 0, stream>>>(out, gamma, beta);
}

// Round 3
// 222.111 us; speedup vs baseline: 1.0511x; 1.0003x over previous
//
#include <hip/hip_runtime.h>

#define B_ 4
#define S_ 2048
#define E_ 512
#define H_ 8
#define HD_ 64

typedef float f32x4 __attribute__((ext_vector_type(4)));
typedef __bf16 bf16x8 __attribute__((ext_vector_type(8)));

#define MFMA16(a, b, c) __builtin_amdgcn_mfma_f32_16x16x32_bf16((a), (b), (c), 0, 0, 0)

__device__ __forceinline__ unsigned f2bfu(float f) {
  union { float f; unsigned u; } x; x.f = f;
  return (x.u + 0x8000u) >> 16;
}
__device__ __forceinline__ unsigned pk2bf(float lo, float hi) {
  union { float f; unsigned u; } a, b; a.f = lo; b.f = hi;
  return ((b.u + 0x8000u) & 0xFFFF0000u) | ((a.u + 0x8000u) >> 16);
}
__device__ __forceinline__ float bf2f(unsigned short s) {
  union { unsigned u; float f; } x; x.u = ((unsigned)s) << 16;
  return x.f;
}
__device__ __forceinline__ float fast_exp2(float x) {
  float r;
  __asm__("v_exp_f32 %0, %1" : "=v"(r) : "v"(x));
  return r;
}
// async global->LDS, 16B per lane. LDS dest = wave-uniform base + lane*16.
__device__ __forceinline__ void gload_lds16(const unsigned short* g, unsigned short* l) {
  __builtin_amdgcn_global_load_lds(
      (const __attribute__((address_space(1))) unsigned int*)g,
      (__attribute__((address_space(3))) unsigned int*)l, 16, 0, 0);
}

// ---------------------------------------------------------------------------
// Fused input conversion. blocks 0..2047: x -> xb (bf16).
// blocks 2048..2431: W (128/matrix); 2432..2495: Er (d-permuted); 2496: zero row.
// ---------------------------------------------------------------------------
__global__ __launch_bounds__(256) void conv_all(
    const float* __restrict__ x, const float* __restrict__ Wq,
    const float* __restrict__ Wk, const float* __restrict__ Wv,
    const float* __restrict__ Er, unsigned short* __restrict__ xb,
    unsigned short* __restrict__ wb, unsigned short* __restrict__ erb)
{
  const int bid = blockIdx.x, tid = threadIdx.x;
  if (bid < 2048) {
    size_t i = ((size_t)bid * 256 + tid) * 8;
    float4 f0 = *(const float4*)&x[i];
    float4 f1 = *(const float4*)&x[i + 4];
    uint4 o;
    o.x = pk2bf(f0.x, f0.y); o.y = pk2bf(f0.z, f0.w);
    o.z = pk2bf(f1.x, f1.y); o.w = pk2bf(f1.z, f1.w);
    *(uint4*)&xb[i] = o;
  } else if (bid < 2432) {
    int wz = bid - 2048;
    int z = wz >> 7, mi = wz & 127;
    const float* src = (z == 0) ? Wq : (z == 1) ? Wk : Wv;
    size_t off = (size_t)mi * 2048 + tid * 8;
    float4 f0 = *(const float4*)&src[off];
    float4 f1 = *(const float4*)&src[off + 4];
    uint4 o;
    o.x = pk2bf(f0.x, f0.y); o.y = pk2bf(f0.z, f0.w);
    o.z = pk2bf(f1.x, f1.y); o.w = pk2bf(f1.z, f1.w);
    *(uint4*)&wb[(size_t)z * 262144 + off] = o;
  } else if (bid < 2496) {
    size_t off = (size_t)(bid - 2432) * 2048 + tid * 8;
    int row = (int)(off >> 6), d0 = (int)(off & 63);
    float4 f0 = *(const float4*)&Er[off];
    float4 f1 = *(const float4*)&Er[off + 4];
    float vals[8] = {f0.x, f0.y, f0.z, f0.w, f1.x, f1.y, f1.z, f1.w};
#pragma unroll
    for (int j = 0; j < 8; ++j) {
      int d = d0 + j;
      int dp = (d & 15) * 4 + (d >> 4);
      erb[(size_t)row * 64 + dp] = (unsigned short)f2bfu(vals[j]);
    }
  } else {
    if (tid < 8) *(uint4*)&erb[2048 * 64 + tid * 8] = make_uint4(0, 0, 0, 0);
  }
}

// ---------------------------------------------------------------------------
// QKV projection, pure-bf16 MFMA with global_load_lds staging.
// out[z] = bf16(xb @ wb[z]^T). M=8192,N=512,K=512. grid (64,4,3), 256 thr.
// ALL z: output d-axis permuted within 64-blocks (d' = (d&15)*4 + d>>4)
// -> packed b64 stores. Q pre-scaled by 512^-0.5 * log2(e).
// V's permutation is undone (free) inside v_transpose's row relabel.
// ---------------------------------------------------------------------------
__global__ __launch_bounds__(256) void qkv_gemm_mfma(
    const unsigned short* __restrict__ xb, const unsigned short* __restrict__ wb,
    unsigned short* __restrict__ qkvb)
{
  const int z = blockIdx.z;
  const unsigned short* W = wb + (size_t)z * 262144;
  unsigned short* out = qkvb + (size_t)z * (8192u * 512u);
  const int m0 = blockIdx.x * 128, n0 = blockIdx.y * 128;

  __shared__ __align__(16) unsigned short As[128 * 64];
  __shared__ __align__(16) unsigned short Bs[128 * 64];

  const int tid = threadIdx.x;
  const int w = tid >> 6, l = tid & 63, lm = l & 15, lq = l >> 4;
  const int wm = w & 1, wn = w >> 1;

  union u4bf { uint4 u; bf16x8 v; };
  f32x4 acc[4][4];
#pragma unroll
  for (int a = 0; a < 4; ++a)
#pragma unroll
    for (int b = 0; b < 4; ++b) acc[a][b] = (f32x4){0.f, 0.f, 0.f, 0.f};

  for (int k0 = 0; k0 < 512; k0 += 64) {
    const unsigned short* xa = xb + (size_t)m0 * 512 + k0;
    const unsigned short* wz = W + (size_t)n0 * 512 + k0;
    __syncthreads();
#pragma unroll
    for (int rr = 0; rr < 4; ++rr) {
      int cb = rr * 256 + w * 64;
      int s = cb + l;
      int row = s >> 3, c = (s & 7) ^ (row & 7);
      gload_lds16(&xa[(size_t)row * 512 + c * 8], &As[cb * 8]);
      gload_lds16(&wz[(size_t)row * 512 + c * 8], &Bs[cb * 8]);
    }
    __syncthreads();
#pragma unroll
    for (int ka = 0; ka < 2; ++ka) {
      u4bf af[4];
#pragma unroll
      for (int mt = 0; mt < 4; ++mt) {
        int row = wm * 64 + mt * 16 + lm;
        af[mt].u = *(const uint4*)&As[row * 64 + (((ka * 4 + lq) ^ (row & 7)) * 8)];
      }
#pragma unroll
      for (int nt = 0; nt < 4; ++nt) {
        int row = wn * 64 + nt * 16 + lm;
        u4bf bfv;
        bfv.u = *(const uint4*)&Bs[row * 64 + (((ka * 4 + lq) ^ (row & 7)) * 8)];
#pragma unroll
        for (int mt = 0; mt < 4; ++mt) acc[mt][nt] = MFMA16(af[mt].v, bfv.v, acc[mt][nt]);
      }
    }
  }
  const float m = (z == 0) ? 0.06376695f : 1.0f;  // 512^-0.5 * log2(e) for Q
#pragma unroll
  for (int mt = 0; mt < 4; ++mt)
#pragma unroll
    for (int reg = 0; reg < 4; ++reg) {
      int row = m0 + wm * 64 + mt * 16 + lq * 4 + reg;
      uint2 v = make_uint2(
          pk2bf(acc[mt][0][reg] * m, acc[mt][1][reg] * m),
          pk2bf(acc[mt][2][reg] * m, acc[mt][3][reg] * m));
      *(uint2*)&out[(size_t)row * 512 + n0 + wn * 64 + lm * 4] = v;
    }
}

// ---------------------------------------------------------------------------
// V transpose with t-permutation baked in; input V arrives d-permuted
// (d' = (d&15)*4 + d>>4) so the output row is relabeled d = (d'&3)*16+(d'>>2)
// (free). grid (32, 8, 4), 256 thr.
// ---------------------------------------------------------------------------
__global__ __launch_bounds__(256) void v_transpose(
    const unsigned short* __restrict__ v, unsigned short* __restrict__ vt)
{
  const int s0 = blockIdx.x * 64, c0 = blockIdx.y * 64, b = blockIdx.z;
  __shared__ __align__(16) unsigned short T[64 * 72];
  const int tid = threadIdx.x;
  for (int idx = tid; idx < 512; idx += 256) {
    int r = idx >> 3, c8 = (idx & 7) * 8;
    *(uint4*)&T[r * 72 + c8] =
        *(const uint4*)&v[(size_t)(b * 2048 + s0 + r) * 512 + c0 + c8];
  }
  __syncthreads();
  for (int idx = tid; idx < 512; idx += 256) {
    int dp = idx >> 3, s8 = (idx & 7) * 8;
    int d = (dp & 3) * 16 + (dp >> 2);  // un-permute
    union { unsigned short u[8]; uint4 q; } tmp;
#pragma unroll
    for (int j = 0; j < 8; ++j) {
      int p = s8 + j;
      int tsrc = (p & 3) * 16 + (p >> 2);
      tmp.u[j] = T[tsrc * 72 + dp];
    }
    *(uint4*)&vt[((size_t)(b * 512) + c0 + d) * 2048 + s0 + s8] = tmp.q;
  }
}

// ---------------------------------------------------------------------------
// Fused attention — R9: R8 structure + XCD-aware block remap + setprio.
// R8 post-mortem: residency fix gained 8us (124us steady); FETCH_SIZE 76.8MB
// vs ~20MB unique => K/V tiles re-fetched by every XCD (qp-fastest dispatch
// round-robins same-bh blocks across XCDs) => per-iter staging runs at
// HBM-miss (~900cy) not L2-hit (~200cy), exposed at barrier (b).
// NEW:
//   - Bijective XCD remap (T1): nf = (L&7)*64 + (L>>3); qp = nf&15,
//     bh = nf>>4. XCD x owns bh in {4x..4x+3} x all 16 qp => each bh's K/V
//     (1MB) resident in ONE XCD L2; staging becomes L2-hit; K/V HBM ~1x.
//   - setprio(1) around QK/PV MFMA clusters (T5; proven +4-7% attn).
// Structure otherwise identical to R8 (2 barriers/iter, Rx stride 68).
// ---------------------------------------------------------------------------
__global__ __launch_bounds__(512, 4) void attn_mfma(
    const unsigned short* __restrict__ qw, const unsigned short* __restrict__ kw,
    const unsigned short* __restrict__ vt, const unsigned short* __restrict__ erb,
    float* __restrict__ out)
{
  // ---- XCD-aware bijective remap (hw round-robins linear id % 8) ----
  const int Lf = blockIdx.y * 16 + blockIdx.x;
  const int nf = (Lf & 7) * 64 + (Lf >> 3);
  const int qp = nf & 15, bh = nf >> 4;
  const int b = bh >> 3, h = bh & 7;

  __shared__ __align__(16) unsigned short Ks[64 * 64];        // [t][d'] swizzled
  __shared__ __align__(16) unsigned short VTs[64 * 64];       // [d][t'] swizzled
  __shared__ __align__(16) unsigned short Ps[2][64 * 72];     // per-group P rows
  __shared__ __align__(16) unsigned short Rx[2][128 * 68];    // per-group [slot][isel]

  const int tid = threadIdx.x;
  const int w = tid >> 6, l = tid & 63, lm = l & 15, lq = l >> 4;
  const int wg = w >> 2, wl = w & 3;   // wave-group (Q-tile), wave-in-group
  const int i0 = (qp * 2 + wg) * 64;

  const unsigned short* qbase = qw + ((size_t)(b * 2048)) * 512 + h * 64;
  const unsigned short* kbase = kw + ((size_t)(b * 2048)) * 512 + h * 64;
  const unsigned short* vtb = vt + ((size_t)(b * 512 + h * 64)) * 2048;

  union u4bf { uint4 u; bf16x8 v; };

  u4bf ones;
  ones.u = make_uint4(0x3F803F80u, 0x3F803F80u, 0x3F803F80u, 0x3F803F80u);

  // ---- loop-invariant address constants ----
  const int ko0 = (lq ^ (lm & 7)) * 8;          // swizzled frag offset, ka=0
  const int ko1 = ((4 + lq) ^ (lm & 7)) * 8;    // ka=1
  const int apa = (wl * 16 + lm) * 72 + lq * 8; // ap read base (ka*32 added)
  unsigned short* PsG = Ps[wg];
  unsigned short* RxG = Rx[wg];
  // gather constants: cn[reg][nt] = 63 + lm - il + 16*nt, il = wl*16+lq*4+reg
  int cn0[4], il_[4], psa[4];
#pragma unroll
  for (int reg = 0; reg < 4; ++reg) {
    il_[reg] = wl * 16 + lq * 4 + reg;
    cn0[reg] = 63 + lm - il_[reg];
    psa[reg] = il_[reg] * 72 + lm * 4;
  }

  // ---- wave's own QK A-fragment ----
  u4bf aqw[2];
  {
    int gi = i0 + wl * 16 + lm;
    aqw[0].u = *(const uint4*)&qbase[(size_t)gi * 512 + lq * 8];
    aqw[1].u = *(const uint4*)&qbase[(size_t)gi * 512 + 32 + lq * 8];
  }
  // ---- Q-ext fragments for rslab (rows rt*16+lm; >64 or OOB -> 0),
  //      constant-indexed ONLY (R2 lesson) ----
  u4bf aq[5][2];
#pragma unroll
  for (int rt = 0; rt < 5; ++rt) {
    int row = rt * 16 + lm, gi = i0 + row;
#pragma unroll
    for (int ka = 0; ka < 2; ++ka) {
      if (row <= 64 && gi < 2048)
        aq[rt][ka].u = *(const uint4*)&qbase[(size_t)gi * 512 + ka * 32 + lq * 8];
      else
        aq[rt][ka].u = make_uint4(0, 0, 0, 0);
    }
  }

  // 8 waves stage a 64x64 tile: one gload_lds16 per wave.
  auto stageTile = [&](const unsigned short* srcBase, size_t srcStride,
                       unsigned short* dst) {
    int cb = w * 64;
    int s = cb + l;
    int row = s >> 3, c = (s & 7) ^ (row & 7);
    gload_lds16(&srcBase[(size_t)row * srcStride + c * 8], &dst[cb * 8]);
  };
  auto loadBe = [&](int A0, u4bf& be0, u4bf& be1) {
    int ai = A0 + wl * 16 + lm;
    int g = (ai < 64) ? (1984 + ai) : (ai == 64 ? 2048 : ai - 65);
    const unsigned short* ep = &erb[(size_t)g * 64];
    be0.u = *(const uint4*)&ep[lq * 8];
    be1.u = *(const uint4*)&ep[32 + lq * 8];
  };
  auto rslabCompute = [&](int A0, u4bf be0, u4bf be1) {
    f32x4 rc[5];
#pragma unroll
    for (int rt = 0; rt < 5; ++rt) rc[rt] = (f32x4){0.f, 0.f, 0.f, 0.f};
    rc[0] = MFMA16(aq[0][0].v, be0.v, rc[0]);
    rc[0] = MFMA16(aq[0][1].v, be1.v, rc[0]);
    rc[1] = MFMA16(aq[1][0].v, be0.v, rc[1]);
    rc[1] = MFMA16(aq[1][1].v, be1.v, rc[1]);
    rc[2] = MFMA16(aq[2][0].v, be0.v, rc[2]);
    rc[2] = MFMA16(aq[2][1].v, be1.v, rc[2]);
    rc[3] = MFMA16(aq[3][0].v, be0.v, rc[3]);
    rc[3] = MFMA16(aq[3][1].v, be1.v, rc[3]);
    rc[4] = MFMA16(aq[4][0].v, be0.v, rc[4]);
    rc[4] = MFMA16(aq[4][1].v, be1.v, rc[4]);
    int slot = (A0 + wl * 16 + lm) & 127;
    unsigned short* rp = &RxG[slot * 68 + lq * 4];
    *(unsigned*)&rp[0]  = pk2bf(rc[0][0], rc[0][1]);
    *(unsigned*)&rp[2]  = pk2bf(rc[0][2], rc[0][3]);
    *(unsigned*)&rp[16] = pk2bf(rc[1][0], rc[1][1]);
    *(unsigned*)&rp[18] = pk2bf(rc[1][2], rc[1][3]);
    *(unsigned*)&rp[32] = pk2bf(rc[2][0], rc[2][1]);
    *(unsigned*)&rp[34] = pk2bf(rc[2][2], rc[2][3]);
    *(unsigned*)&rp[48] = pk2bf(rc[3][0], rc[3][1]);
    *(unsigned*)&rp[50] = pk2bf(rc[3][2], rc[3][3]);
    if (lq == 0) RxG[slot * 68 + 64] = (unsigned short)f2bfu(rc[4][0]);
  };

  // ---- prefill Rx[wg] with ai in [-i0, -i0+127] (disjoint slots) ----
  {
    u4bf b0, b1;
    loadBe(-i0, b0, b1);
    rslabCompute(-i0, b0, b1);
    loadBe(-i0 + 64, b0, b1);
    rslabCompute(-i0 + 64, b0, b1);
  }
  // prefetch Er B-fragments for tb=1 (A0 = -i0+127)
  u4bf pb0, pb1;
  loadBe(-i0 + 127, pb0, pb1);

  f32x4 O[5];  // O[4] = row-sum l accumulator
#pragma unroll
  for (int a = 0; a < 5; ++a) O[a] = (f32x4){0.f, 0.f, 0.f, 0.f};

  for (int tb = 0; tb < 32; ++tb) {
    const int t0 = tb * 64, dbase = t0 - i0;
    __syncthreads();  // (a) prior-iter consumers (QK/PV/gather) done

    stageTile(kbase + (size_t)t0 * 512, 512, Ks);
    stageTile(vtb + t0, 2048, VTs);
    if (tb > 0) {
      rslabCompute(dbase + 63, pb0, pb1);
      if (tb < 31) loadBe(dbase + 127, pb0, pb1);  // prefetch next iter
    }
    __syncthreads();  // (b) staging DMA drained + Rx visible

    // ---- QK^T (hoisted swizzle offsets) ----
    f32x4 sc[4];
    __builtin_amdgcn_s_setprio(1);
#pragma unroll
    for (int nt = 0; nt < 4; ++nt) {
      int rb = (nt * 16 + lm) * 64;
      u4bf bk0, bk1;
      bk0.u = *(const uint4*)&Ks[rb + ko0];
      bk1.u = *(const uint4*)&Ks[rb + ko1];
      sc[nt] = (f32x4){0.f, 0.f, 0.f, 0.f};
      sc[nt] = MFMA16(aqw[0].v, bk0.v, sc[nt]);
      sc[nt] = MFMA16(aqw[1].v, bk1.v, sc[nt]);
    }
    __builtin_amdgcn_s_setprio(0);

    // ---- skew gather + exp2, packed b64 P-write (wave-private rows) ----
#pragma unroll
    for (int reg = 0; reg < 4; ++reg) {
      const int aib = dbase + cn0[reg];
      const int il = il_[reg];
      float pv[4];
#pragma unroll
      for (int nt = 0; nt < 4; ++nt) {
        int ai = aib + nt * 16;
        int isel = il + (ai >= 65 ? 1 : 0);
        float rel = bf2f(RxG[(ai & 127) * 68 + isel]);
        pv[nt] = fast_exp2(sc[nt][reg] + rel);
      }
      *(uint2*)&PsG[psa[reg]] =
          make_uint2(pk2bf(pv[0], pv[1]), pk2bf(pv[2], pv[3]));
    }
    __asm__ __volatile__("" ::: "memory");  // same-wave DS RAW: in-order DS pipe

    // ---- PV + l (ones from registers) ----
    __builtin_amdgcn_s_setprio(1);
#pragma unroll
    for (int ka = 0; ka < 2; ++ka) {
      u4bf ap;
      ap.u = *(const uint4*)&PsG[apa + ka * 32];
#pragma unroll
      for (int nt = 0; nt < 4; ++nt) {
        int rb = (nt * 16 + lm) * 64;
        u4bf bv;
        bv.u = *(const uint4*)&VTs[rb + (ka == 0 ? ko0 : ko1)];
        O[nt] = MFMA16(ap.v, bv.v, O[nt]);
      }
      O[4] = MFMA16(ap.v, ones.v, O[4]);
    }
    __builtin_amdgcn_s_setprio(0);
  }

  // epilogue: every lane holds l in O[4][reg]
  float* ob = out + ((size_t)(b * 2048) + i0) * 512 + h * 64;
#pragma unroll
  for (int reg = 0; reg < 4; ++reg) {
    float inv = 1.f / O[4][reg];
#pragma unroll
    for (int nt = 0; nt < 4; ++nt)
      ob[(size_t)il_[reg] * 512 + nt * 16 + lm] = O[nt][reg] * inv;
  }
}

// ---------------------------------------------------------------------------
// In-place LayerNorm over E=512 per (b,s) row. grid 8192, block 256.
// ---------------------------------------------------------------------------
__global__ __launch_bounds__(256) void ln_kernel(
    float* __restrict__ io, const float* __restrict__ gamma,
    const float* __restrict__ beta)
{
  const int row = blockIdx.x;
  float* xr = io + (size_t)row * 512;
  const int tid = threadIdx.x;
  float2 v = *(const float2*)&xr[tid * 2];
  float s = v.x + v.y;
  float sq = v.x * v.x + v.y * v.y;
#pragma unroll
  for (int off = 1; off < 64; off <<= 1) {
    s += __shfl_xor(s, off, 64);
    sq += __shfl_xor(sq, off, 64);
  }
  __shared__ float red[8];
  const int wid = tid >> 6, lane = tid & 63;
  if (lane == 0) { red[wid] = s; red[wid + 4] = sq; }
  __syncthreads();
  s = red[0] + red[1] + red[2] + red[3];
  sq = red[4] + red[5] + red[6] + red[7];
  const float mean = s * (1.f / 512.f);
  float var = sq * (1.f / 512.f) - mean * mean;
  var = fmaxf(var, 0.f);
  const float rstd = rsqrtf(var + 1e-5f);
  float2 g = *(const float2*)&gamma[tid * 2];
  float2 be = *(const float2*)&beta[tid * 2];
  float2 o;
  o.x = (v.x - mean) * rstd * g.x + be.x;
  o.y = (v.y - mean) * rstd * g.y + be.y;
  *(float2*)&xr[tid * 2] = o;
}

extern "C" void kernel_launch(void* const* d_in, const int* in_sizes, int n_in,
                              void* d_out, int out_size, void* d_ws, size_t ws_size,
                              hipStream_t stream) {
  const float* x     = (const float*)d_in[0];
  const float* Wq    = (const float*)d_in[1];
  const float* Wk    = (const float*)d_in[2];
  const float* Wv    = (const float*)d_in[3];
  const float* Er    = (const float*)d_in[4];
  const float* gamma = (const float*)d_in[5];
  const float* beta  = (const float*)d_in[6];
  float* out = (float*)d_out;

  // ws layout (bf16 shorts): qkv 3*8192*512 | vT 4*512*2048 | erb 2049*64 |
  //                          xb 8192*512 | wb 3*512*512      (~41.8 MB)
  unsigned short* qkvb = (unsigned short*)d_ws;
  unsigned short* vtb  = qkvb + (size_t)3 * 8192 * 512;
  unsigned short* erb  = vtb + (size_t)4 * 512 * 2048;
  unsigned short* xb   = erb + (size_t)2049 * 64;
  unsigned short* wb   = xb + (size_t)8192 * 512;
  unsigned short* vb   = qkvb + (size_t)2 * 8192 * 512;

  conv_all<<<dim3(2497), 256, 0, stream>>>(x, Wq, Wk, Wv, Er, xb, wb, erb);
  qkv_gemm_mfma<<<dim3(64, 4, 3), 256, 0, stream>>>(xb, wb, qkvb);
  v_transpose<<<dim3(32, 8, 4), 256, 0, stream>>>(vb, vtb);
  attn_mfma<<<dim3(16, 32), 512, 0, stream>>>(qkvb, qkvb + (size_t)8192 * 512, vtb, erb, out);
  ln_kernel<<<dim3(8192), 256, 0, stream>>>(out, gamma, beta);
}

// Round 4
// 221.129 us; speedup vs baseline: 1.0558x; 1.0044x over previous
//
#include <hip/hip_runtime.h>

#define B_ 4
#define S_ 2048
#define E_ 512
#define H_ 8
#define HD_ 64

typedef float f32x4 __attribute__((ext_vector_type(4)));
typedef __bf16 bf16x8 __attribute__((ext_vector_type(8)));

#define MFMA16(a, b, c) __builtin_amdgcn_mfma_f32_16x16x32_bf16((a), (b), (c), 0, 0, 0)

__device__ __forceinline__ unsigned f2bfu(float f) {
  union { float f; unsigned u; } x; x.f = f;
  return (x.u + 0x8000u) >> 16;
}
__device__ __forceinline__ unsigned pk2bf(float lo, float hi) {
  union { float f; unsigned u; } a, b; a.f = lo; b.f = hi;
  return ((b.u + 0x8000u) & 0xFFFF0000u) | ((a.u + 0x8000u) >> 16);
}
// 4x f32 -> 4x bf16 (RNE) packed in uint2; compiler emits v_cvt_pk_bf16_f32.
__device__ __forceinline__ uint2 pk4bf(float a, float b, float c, float d) {
  union { __bf16 h[4]; uint2 q; } u;
  u.h[0] = (__bf16)a; u.h[1] = (__bf16)b; u.h[2] = (__bf16)c; u.h[3] = (__bf16)d;
  return u.q;
}
__device__ __forceinline__ float bf2f(unsigned short s) {
  union { unsigned u; float f; } x; x.u = ((unsigned)s) << 16;
  return x.f;
}
__device__ __forceinline__ float fast_exp2(float x) {
  float r;
  __asm__("v_exp_f32 %0, %1" : "=v"(r) : "v"(x));
  return r;
}
// async global->LDS, 16B per lane. LDS dest = wave-uniform base + lane*16.
__device__ __forceinline__ void gload_lds16(const unsigned short* g, unsigned short* l) {
  __builtin_amdgcn_global_load_lds(
      (const __attribute__((address_space(1))) unsigned int*)g,
      (__attribute__((address_space(3))) unsigned int*)l, 16, 0, 0);
}

// ---------------------------------------------------------------------------
// Fused input conversion. blocks 0..2047: x -> xb (bf16).
// blocks 2048..2431: W (128/matrix); 2432..2495: Er (d-permuted); 2496: zero row.
// ---------------------------------------------------------------------------
__global__ __launch_bounds__(256) void conv_all(
    const float* __restrict__ x, const float* __restrict__ Wq,
    const float* __restrict__ Wk, const float* __restrict__ Wv,
    const float* __restrict__ Er, unsigned short* __restrict__ xb,
    unsigned short* __restrict__ wb, unsigned short* __restrict__ erb)
{
  const int bid = blockIdx.x, tid = threadIdx.x;
  if (bid < 2048) {
    size_t i = ((size_t)bid * 256 + tid) * 8;
    float4 f0 = *(const float4*)&x[i];
    float4 f1 = *(const float4*)&x[i + 4];
    uint4 o;
    o.x = pk2bf(f0.x, f0.y); o.y = pk2bf(f0.z, f0.w);
    o.z = pk2bf(f1.x, f1.y); o.w = pk2bf(f1.z, f1.w);
    *(uint4*)&xb[i] = o;
  } else if (bid < 2432) {
    int wz = bid - 2048;
    int z = wz >> 7, mi = wz & 127;
    const float* src = (z == 0) ? Wq : (z == 1) ? Wk : Wv;
    size_t off = (size_t)mi * 2048 + tid * 8;
    float4 f0 = *(const float4*)&src[off];
    float4 f1 = *(const float4*)&src[off + 4];
    uint4 o;
    o.x = pk2bf(f0.x, f0.y); o.y = pk2bf(f0.z, f0.w);
    o.z = pk2bf(f1.x, f1.y); o.w = pk2bf(f1.z, f1.w);
    *(uint4*)&wb[(size_t)z * 262144 + off] = o;
  } else if (bid < 2496) {
    size_t off = (size_t)(bid - 2432) * 2048 + tid * 8;
    int row = (int)(off >> 6), d0 = (int)(off & 63);
    float4 f0 = *(const float4*)&Er[off];
    float4 f1 = *(const float4*)&Er[off + 4];
    float vals[8] = {f0.x, f0.y, f0.z, f0.w, f1.x, f1.y, f1.z, f1.w};
#pragma unroll
    for (int j = 0; j < 8; ++j) {
      int d = d0 + j;
      int dp = (d & 15) * 4 + (d >> 4);
      erb[(size_t)row * 64 + dp] = (unsigned short)f2bfu(vals[j]);
    }
  } else {
    if (tid < 8) *(uint4*)&erb[2048 * 64 + tid * 8] = make_uint4(0, 0, 0, 0);
  }
}

// ---------------------------------------------------------------------------
// QKV projection, pure-bf16 MFMA with global_load_lds staging.
// out[z] = bf16(xb @ wb[z]^T). M=8192,N=512,K=512. grid (64,4,3), 256 thr.
// ALL z: output d-axis permuted within 64-blocks (d' = (d&15)*4 + d>>4)
// -> packed b64 stores. Q pre-scaled by 512^-0.5 * log2(e).
// V's permutation is undone (free) inside v_transpose's row relabel.
// ---------------------------------------------------------------------------
__global__ __launch_bounds__(256) void qkv_gemm_mfma(
    const unsigned short* __restrict__ xb, const unsigned short* __restrict__ wb,
    unsigned short* __restrict__ qkvb)
{
  const int z = blockIdx.z;
  const unsigned short* W = wb + (size_t)z * 262144;
  unsigned short* out = qkvb + (size_t)z * (8192u * 512u);
  const int m0 = blockIdx.x * 128, n0 = blockIdx.y * 128;

  __shared__ __align__(16) unsigned short As[128 * 64];
  __shared__ __align__(16) unsigned short Bs[128 * 64];

  const int tid = threadIdx.x;
  const int w = tid >> 6, l = tid & 63, lm = l & 15, lq = l >> 4;
  const int wm = w & 1, wn = w >> 1;

  union u4bf { uint4 u; bf16x8 v; };
  f32x4 acc[4][4];
#pragma unroll
  for (int a = 0; a < 4; ++a)
#pragma unroll
    for (int b = 0; b < 4; ++b) acc[a][b] = (f32x4){0.f, 0.f, 0.f, 0.f};

  for (int k0 = 0; k0 < 512; k0 += 64) {
    const unsigned short* xa = xb + (size_t)m0 * 512 + k0;
    const unsigned short* wz = W + (size_t)n0 * 512 + k0;
    __syncthreads();
#pragma unroll
    for (int rr = 0; rr < 4; ++rr) {
      int cb = rr * 256 + w * 64;
      int s = cb + l;
      int row = s >> 3, c = (s & 7) ^ (row & 7);
      gload_lds16(&xa[(size_t)row * 512 + c * 8], &As[cb * 8]);
      gload_lds16(&wz[(size_t)row * 512 + c * 8], &Bs[cb * 8]);
    }
    __syncthreads();
#pragma unroll
    for (int ka = 0; ka < 2; ++ka) {
      u4bf af[4];
#pragma unroll
      for (int mt = 0; mt < 4; ++mt) {
        int row = wm * 64 + mt * 16 + lm;
        af[mt].u = *(const uint4*)&As[row * 64 + (((ka * 4 + lq) ^ (row & 7)) * 8)];
      }
#pragma unroll
      for (int nt = 0; nt < 4; ++nt) {
        int row = wn * 64 + nt * 16 + lm;
        u4bf bfv;
        bfv.u = *(const uint4*)&Bs[row * 64 + (((ka * 4 + lq) ^ (row & 7)) * 8)];
#pragma unroll
        for (int mt = 0; mt < 4; ++mt) acc[mt][nt] = MFMA16(af[mt].v, bfv.v, acc[mt][nt]);
      }
    }
  }
  const float m = (z == 0) ? 0.06376695f : 1.0f;  // 512^-0.5 * log2(e) for Q
#pragma unroll
  for (int mt = 0; mt < 4; ++mt)
#pragma unroll
    for (int reg = 0; reg < 4; ++reg) {
      int row = m0 + wm * 64 + mt * 16 + lq * 4 + reg;
      uint2 v = make_uint2(
          pk2bf(acc[mt][0][reg] * m, acc[mt][1][reg] * m),
          pk2bf(acc[mt][2][reg] * m, acc[mt][3][reg] * m));
      *(uint2*)&out[(size_t)row * 512 + n0 + wn * 64 + lm * 4] = v;
    }
}

// ---------------------------------------------------------------------------
// V transpose with t-permutation baked in; input V arrives d-permuted
// (d' = (d&15)*4 + d>>4) so the output row is relabeled d = (d'&3)*16+(d'>>2)
// (free). grid (32, 8, 4), 256 thr.
// ---------------------------------------------------------------------------
__global__ __launch_bounds__(256) void v_transpose(
    const unsigned short* __restrict__ v, unsigned short* __restrict__ vt)
{
  const int s0 = blockIdx.x * 64, c0 = blockIdx.y * 64, b = blockIdx.z;
  __shared__ __align__(16) unsigned short T[64 * 72];
  const int tid = threadIdx.x;
  for (int idx = tid; idx < 512; idx += 256) {
    int r = idx >> 3, c8 = (idx & 7) * 8;
    *(uint4*)&T[r * 72 + c8] =
        *(const uint4*)&v[(size_t)(b * 2048 + s0 + r) * 512 + c0 + c8];
  }
  __syncthreads();
  for (int idx = tid; idx < 512; idx += 256) {
    int dp = idx >> 3, s8 = (idx & 7) * 8;
    int d = (dp & 3) * 16 + (dp >> 2);  // un-permute
    union { unsigned short u[8]; uint4 q; } tmp;
#pragma unroll
    for (int j = 0; j < 8; ++j) {
      int p = s8 + j;
      int tsrc = (p & 3) * 16 + (p >> 2);
      tmp.u[j] = T[tsrc * 72 + dp];
    }
    *(uint4*)&vt[((size_t)(b * 512) + c0 + d) * 2048 + s0 + s8] = tmp.q;
  }
}

// ---------------------------------------------------------------------------
// Fused attention — R10: DS + VALU trim on the R9 structure.
// R9 post-mortem: XCD remap cut FETCH 4x (76.8->19.0MB) but time ~flat
// (staging latency was TLP-hidden). Pipe arithmetic: DS ~70% (16 waves x
// ~363cy + 640cy conflicts vs 9230cy wall), VALU 54%, MFMA 20% -> jointly
// DS+VALU limited.
// NEW (only changes):
//   - rslab Rx writes: 8x ds_write_b32 -> 4x ds_write_b64 (contiguous
//     8B-aligned quads at +0/+32/+64/+96 B).
//   - bf16 packing in the hot loop via native (__bf16) casts (pk4bf) ->
//     compiler emits v_cvt_pk_bf16_f32 (1 op vs ~4-5 manual bit-ops/pair),
//     RNE rounding. ~50 VALU/wave/iter saved.
// Kept: XCD bijective remap, setprio, 2 barriers/iter, Rx stride 68.
// ---------------------------------------------------------------------------
__global__ __launch_bounds__(512, 4) void attn_mfma(
    const unsigned short* __restrict__ qw, const unsigned short* __restrict__ kw,
    const unsigned short* __restrict__ vt, const unsigned short* __restrict__ erb,
    float* __restrict__ out)
{
  // ---- XCD-aware bijective remap (hw round-robins linear id % 8) ----
  const int Lf = blockIdx.y * 16 + blockIdx.x;
  const int nf = (Lf & 7) * 64 + (Lf >> 3);
  const int qp = nf & 15, bh = nf >> 4;
  const int b = bh >> 3, h = bh & 7;

  __shared__ __align__(16) unsigned short Ks[64 * 64];        // [t][d'] swizzled
  __shared__ __align__(16) unsigned short VTs[64 * 64];       // [d][t'] swizzled
  __shared__ __align__(16) unsigned short Ps[2][64 * 72];     // per-group P rows
  __shared__ __align__(16) unsigned short Rx[2][128 * 68];    // per-group [slot][isel]

  const int tid = threadIdx.x;
  const int w = tid >> 6, l = tid & 63, lm = l & 15, lq = l >> 4;
  const int wg = w >> 2, wl = w & 3;   // wave-group (Q-tile), wave-in-group
  const int i0 = (qp * 2 + wg) * 64;

  const unsigned short* qbase = qw + ((size_t)(b * 2048)) * 512 + h * 64;
  const unsigned short* kbase = kw + ((size_t)(b * 2048)) * 512 + h * 64;
  const unsigned short* vtb = vt + ((size_t)(b * 512 + h * 64)) * 2048;

  union u4bf { uint4 u; bf16x8 v; };

  u4bf ones;
  ones.u = make_uint4(0x3F803F80u, 0x3F803F80u, 0x3F803F80u, 0x3F803F80u);

  // ---- loop-invariant address constants ----
  const int ko0 = (lq ^ (lm & 7)) * 8;          // swizzled frag offset, ka=0
  const int ko1 = ((4 + lq) ^ (lm & 7)) * 8;    // ka=1
  const int apa = (wl * 16 + lm) * 72 + lq * 8; // ap read base (ka*32 added)
  unsigned short* PsG = Ps[wg];
  unsigned short* RxG = Rx[wg];
  // gather constants: cn[reg][nt] = 63 + lm - il + 16*nt, il = wl*16+lq*4+reg
  int cn0[4], il_[4], psa[4];
#pragma unroll
  for (int reg = 0; reg < 4; ++reg) {
    il_[reg] = wl * 16 + lq * 4 + reg;
    cn0[reg] = 63 + lm - il_[reg];
    psa[reg] = il_[reg] * 72 + lm * 4;
  }

  // ---- wave's own QK A-fragment ----
  u4bf aqw[2];
  {
    int gi = i0 + wl * 16 + lm;
    aqw[0].u = *(const uint4*)&qbase[(size_t)gi * 512 + lq * 8];
    aqw[1].u = *(const uint4*)&qbase[(size_t)gi * 512 + 32 + lq * 8];
  }
  // ---- Q-ext fragments for rslab (rows rt*16+lm; >64 or OOB -> 0),
  //      constant-indexed ONLY (R2 lesson) ----
  u4bf aq[5][2];
#pragma unroll
  for (int rt = 0; rt < 5; ++rt) {
    int row = rt * 16 + lm, gi = i0 + row;
#pragma unroll
    for (int ka = 0; ka < 2; ++ka) {
      if (row <= 64 && gi < 2048)
        aq[rt][ka].u = *(const uint4*)&qbase[(size_t)gi * 512 + ka * 32 + lq * 8];
      else
        aq[rt][ka].u = make_uint4(0, 0, 0, 0);
    }
  }

  // 8 waves stage a 64x64 tile: one gload_lds16 per wave.
  auto stageTile = [&](const unsigned short* srcBase, size_t srcStride,
                       unsigned short* dst) {
    int cb = w * 64;
    int s = cb + l;
    int row = s >> 3, c = (s & 7) ^ (row & 7);
    gload_lds16(&srcBase[(size_t)row * srcStride + c * 8], &dst[cb * 8]);
  };
  auto loadBe = [&](int A0, u4bf& be0, u4bf& be1) {
    int ai = A0 + wl * 16 + lm;
    int g = (ai < 64) ? (1984 + ai) : (ai == 64 ? 2048 : ai - 65);
    const unsigned short* ep = &erb[(size_t)g * 64];
    be0.u = *(const uint4*)&ep[lq * 8];
    be1.u = *(const uint4*)&ep[32 + lq * 8];
  };
  auto rslabCompute = [&](int A0, u4bf be0, u4bf be1) {
    f32x4 rc[5];
#pragma unroll
    for (int rt = 0; rt < 5; ++rt) rc[rt] = (f32x4){0.f, 0.f, 0.f, 0.f};
    rc[0] = MFMA16(aq[0][0].v, be0.v, rc[0]);
    rc[0] = MFMA16(aq[0][1].v, be1.v, rc[0]);
    rc[1] = MFMA16(aq[1][0].v, be0.v, rc[1]);
    rc[1] = MFMA16(aq[1][1].v, be1.v, rc[1]);
    rc[2] = MFMA16(aq[2][0].v, be0.v, rc[2]);
    rc[2] = MFMA16(aq[2][1].v, be1.v, rc[2]);
    rc[3] = MFMA16(aq[3][0].v, be0.v, rc[3]);
    rc[3] = MFMA16(aq[3][1].v, be1.v, rc[3]);
    rc[4] = MFMA16(aq[4][0].v, be0.v, rc[4]);
    rc[4] = MFMA16(aq[4][1].v, be1.v, rc[4]);
    int slot = (A0 + wl * 16 + lm) & 127;
    unsigned short* rp = &RxG[slot * 68 + lq * 4];
    *(uint2*)&rp[0]  = pk4bf(rc[0][0], rc[0][1], rc[0][2], rc[0][3]);
    *(uint2*)&rp[16] = pk4bf(rc[1][0], rc[1][1], rc[1][2], rc[1][3]);
    *(uint2*)&rp[32] = pk4bf(rc[2][0], rc[2][1], rc[2][2], rc[2][3]);
    *(uint2*)&rp[48] = pk4bf(rc[3][0], rc[3][1], rc[3][2], rc[3][3]);
    if (lq == 0) RxG[slot * 68 + 64] = (unsigned short)f2bfu(rc[4][0]);
  };

  // ---- prefill Rx[wg] with ai in [-i0, -i0+127] (disjoint slots) ----
  {
    u4bf b0, b1;
    loadBe(-i0, b0, b1);
    rslabCompute(-i0, b0, b1);
    loadBe(-i0 + 64, b0, b1);
    rslabCompute(-i0 + 64, b0, b1);
  }
  // prefetch Er B-fragments for tb=1 (A0 = -i0+127)
  u4bf pb0, pb1;
  loadBe(-i0 + 127, pb0, pb1);

  f32x4 O[5];  // O[4] = row-sum l accumulator
#pragma unroll
  for (int a = 0; a < 5; ++a) O[a] = (f32x4){0.f, 0.f, 0.f, 0.f};

  for (int tb = 0; tb < 32; ++tb) {
    const int t0 = tb * 64, dbase = t0 - i0;
    __syncthreads();  // (a) prior-iter consumers (QK/PV/gather) done

    stageTile(kbase + (size_t)t0 * 512, 512, Ks);
    stageTile(vtb + t0, 2048, VTs);
    if (tb > 0) {
      rslabCompute(dbase + 63, pb0, pb1);
      if (tb < 31) loadBe(dbase + 127, pb0, pb1);  // prefetch next iter
    }
    __syncthreads();  // (b) staging DMA drained + Rx visible

    // ---- QK^T (hoisted swizzle offsets) ----
    f32x4 sc[4];
    __builtin_amdgcn_s_setprio(1);
#pragma unroll
    for (int nt = 0; nt < 4; ++nt) {
      int rb = (nt * 16 + lm) * 64;
      u4bf bk0, bk1;
      bk0.u = *(const uint4*)&Ks[rb + ko0];
      bk1.u = *(const uint4*)&Ks[rb + ko1];
      sc[nt] = (f32x4){0.f, 0.f, 0.f, 0.f};
      sc[nt] = MFMA16(aqw[0].v, bk0.v, sc[nt]);
      sc[nt] = MFMA16(aqw[1].v, bk1.v, sc[nt]);
    }
    __builtin_amdgcn_s_setprio(0);

    // ---- skew gather + exp2, packed b64 P-write (wave-private rows) ----
#pragma unroll
    for (int reg = 0; reg < 4; ++reg) {
      const int aib = dbase + cn0[reg];
      const int il = il_[reg];
      float pv[4];
#pragma unroll
      for (int nt = 0; nt < 4; ++nt) {
        int ai = aib + nt * 16;
        int isel = il + (ai >= 65 ? 1 : 0);
        float rel = bf2f(RxG[(ai & 127) * 68 + isel]);
        pv[nt] = fast_exp2(sc[nt][reg] + rel);
      }
      *(uint2*)&PsG[psa[reg]] = pk4bf(pv[0], pv[1], pv[2], pv[3]);
    }
    __asm__ __volatile__("" ::: "memory");  // same-wave DS RAW: in-order DS pipe

    // ---- PV + l (ones from registers) ----
    __builtin_amdgcn_s_setprio(1);
#pragma unroll
    for (int ka = 0; ka < 2; ++ka) {
      u4bf ap;
      ap.u = *(const uint4*)&PsG[apa + ka * 32];
#pragma unroll
      for (int nt = 0; nt < 4; ++nt) {
        int rb = (nt * 16 + lm) * 64;
        u4bf bv;
        bv.u = *(const uint4*)&VTs[rb + (ka == 0 ? ko0 : ko1)];
        O[nt] = MFMA16(ap.v, bv.v, O[nt]);
      }
      O[4] = MFMA16(ap.v, ones.v, O[4]);
    }
    __builtin_amdgcn_s_setprio(0);
  }

  // epilogue: every lane holds l in O[4][reg]
  float* ob = out + ((size_t)(b * 2048) + i0) * 512 + h * 64;
#pragma unroll
  for (int reg = 0; reg < 4; ++reg) {
    float inv = 1.f / O[4][reg];
#pragma unroll
    for (int nt = 0; nt < 4; ++nt)
      ob[(size_t)il_[reg] * 512 + nt * 16 + lm] = O[nt][reg] * inv;
  }
}

// ---------------------------------------------------------------------------
// In-place LayerNorm over E=512 per (b,s) row. grid 8192, block 256.
// ---------------------------------------------------------------------------
__global__ __launch_bounds__(256) void ln_kernel(
    float* __restrict__ io, const float* __restrict__ gamma,
    const float* __restrict__ beta)
{
  const int row = blockIdx.x;
  float* xr = io + (size_t)row * 512;
  const int tid = threadIdx.x;
  float2 v = *(const float2*)&xr[tid * 2];
  float s = v.x + v.y;
  float sq = v.x * v.x + v.y * v.y;
#pragma unroll
  for (int off = 1; off < 64; off <<= 1) {
    s += __shfl_xor(s, off, 64);
    sq += __shfl_xor(sq, off, 64);
  }
  __shared__ float red[8];
  const int wid = tid >> 6, lane = tid & 63;
  if (lane == 0) { red[wid] = s; red[wid + 4] = sq; }
  __syncthreads();
  s = red[0] + red[1] + red[2] + red[3];
  sq = red[4] + red[5] + red[6] + red[7];
  const float mean = s * (1.f / 512.f);
  float var = sq * (1.f / 512.f) - mean * mean;
  var = fmaxf(var, 0.f);
  const float rstd = rsqrtf(var + 1e-5f);
  float2 g = *(const float2*)&gamma[tid * 2];
  float2 be = *(const float2*)&beta[tid * 2];
  float2 o;
  o.x = (v.x - mean) * rstd * g.x + be.x;
  o.y = (v.y - mean) * rstd * g.y + be.y;
  *(float2*)&xr[tid * 2] = o;
}

extern "C" void kernel_launch(void* const* d_in, const int* in_sizes, int n_in,
                              void* d_out, int out_size, void* d_ws, size_t ws_size,
                              hipStream_t stream) {
  const float* x     = (const float*)d_in[0];
  const float* Wq    = (const float*)d_in[1];
  const float* Wk    = (const float*)d_in[2];
  const float* Wv    = (const float*)d_in[3];
  const float* Er    = (const float*)d_in[4];
  const float* gamma = (const float*)d_in[5];
  const float* beta  = (const float*)d_in[6];
  float* out = (float*)d_out;

  // ws layout (bf16 shorts): qkv 3*8192*512 | vT 4*512*2048 | erb 2049*64 |
  //                          xb 8192*512 | wb 3*512*512      (~41.8 MB)
  unsigned short* qkvb = (unsigned short*)d_ws;
  unsigned short* vtb  = qkvb + (size_t)3 * 8192 * 512;
  unsigned short* erb  = vtb + (size_t)4 * 512 * 2048;
  unsigned short* xb   = erb + (size_t)2049 * 64;
  unsigned short* wb   = xb + (size_t)8192 * 512;
  unsigned short* vb   = qkvb + (size_t)2 * 8192 * 512;

  conv_all<<<dim3(2497), 256, 0, stream>>>(x, Wq, Wk, Wv, Er, xb, wb, erb);
  qkv_gemm_mfma<<<dim3(64, 4, 3), 256, 0, stream>>>(xb, wb, qkvb);
  v_transpose<<<dim3(32, 8, 4), 256, 0, stream>>>(vb, vtb);
  attn_mfma<<<dim3(16, 32), 512, 0, stream>>>(qkvb, qkvb + (size_t)8192 * 512, vtb, erb, out);
  ln_kernel<<<dim3(8192), 256, 0, stream>>>(out, gamma, beta);
}